// Round 7
// baseline (113360.278 us; speedup 1.0000x reference)
//
#include <hip/hip_runtime.h>
#include <hip/hip_fp16.h>

// ---------------- parameters (all inputs fp32; output fp32) ----------------
struct P19 {
  const float *src;
  const float *eWih0, *eWhh0, *ebih0, *ebhh0;
  const float *eWih1, *eWhh1, *ebih1, *ebhh1;
  const float *dWih0, *dWhh0, *dbih0, *dbhh0;
  const float *dWih1, *dWhh1, *dbih1, *dbhh1;
  const float *fcW, *fcb;
  float *out;
  float *ws;
};

typedef _Float16 h2v __attribute__((ext_vector_type(2)));

__device__ __forceinline__ float sigf(float x) { return 1.f / (1.f + __expf(-x)); }

__device__ __forceinline__ unsigned packh(float a, float b2) {
  __half2 h2 = __floats2half2_rn(a, b2);
  return *(const unsigned *)&h2;
}

__device__ __forceinline__ float dot2(unsigned h, unsigned w, float acc) {
#if __has_builtin(__builtin_amdgcn_fdot2)
  return __builtin_amdgcn_fdot2(*(h2v *)&h, *(h2v *)&w, acc, false);
#else
  float2 hf = __half22float2(*(const __half2 *)&h);
  float2 wf = __half22float2(*(const __half2 *)&w);
  return fmaf(hf.x, wf.x, fmaf(hf.y, wf.y, acc));
#endif
}

// ---- split-phase distributed-flag grid barrier (1 block/CU by LDS>80KB) ---
__device__ __forceinline__ void arrive(unsigned *flags, unsigned gen, int tid, int blk) {
  __syncthreads();  // drains all waves' stores (vmcnt) before flag
  if (tid == 0) {
    __threadfence();  // release: push h writes to coherence point
    __hip_atomic_store(flags + blk * 32, gen, __ATOMIC_RELEASE, __HIP_MEMORY_SCOPE_AGENT);
  }
}
__device__ __forceinline__ void waitbar(unsigned *flags, unsigned gen, int tid) {
  if (tid < 256) {
    unsigned *f = flags + tid * 32;
    int g = 0;
    while (__hip_atomic_load(f, __ATOMIC_RELAXED, __HIP_MEMORY_SCOPE_AGENT) < gen) {
      __builtin_amdgcn_s_sleep(4);
      if (++g > (1 << 16)) break;  // safety: never deadlock the bench
    }
  }
  __syncthreads();
  if (tid == 0) __threadfence();  // acquire: invalidate caches before reads
  __syncthreads();
}

// ---- quarter-dots: thread covers BOTH units (8 gate-rows) over 64 k2 ----
// weights per k2: 2x uint4 (unit0 g0..g3, unit1 g0..g3), same-addr broadcast
__device__ __forceinline__ void dotq1(float *A, const uint4 *__restrict__ wq,
                                      const unsigned *__restrict__ hq) {
  unsigned ca[64];
#pragma unroll
  for (int c = 0; c < 64; ++c) ca[c] = hq[c * 128];
#pragma unroll
  for (int c = 0; c < 64; ++c) {
    uint4 w0 = wq[c * 2], w1 = wq[c * 2 + 1];
    unsigned h = ca[c];
    A[0] = dot2(h, w0.x, A[0]); A[1] = dot2(h, w0.y, A[1]);
    A[2] = dot2(h, w0.z, A[2]); A[3] = dot2(h, w0.w, A[3]);
    A[4] = dot2(h, w1.x, A[4]); A[5] = dot2(h, w1.y, A[5]);
    A[6] = dot2(h, w1.z, A[6]); A[7] = dot2(h, w1.w, A[7]);
  }
}
__device__ __forceinline__ void dotq2(float *A, const uint4 *__restrict__ w0q,
                                      const uint4 *__restrict__ w1q,
                                      const unsigned *__restrict__ hq) {
  unsigned ca[64];
#pragma unroll
  for (int c = 0; c < 64; ++c) ca[c] = hq[c * 128];
#pragma unroll
  for (int c = 0; c < 64; ++c) {
    uint4 a0 = w0q[c * 2], a1 = w0q[c * 2 + 1];
    uint4 b0 = w1q[c * 2], b1 = w1q[c * 2 + 1];
    unsigned h = ca[c];
    A[0] = dot2(h, a0.x, A[0]);  A[1] = dot2(h, a0.y, A[1]);
    A[2] = dot2(h, a0.z, A[2]);  A[3] = dot2(h, a0.w, A[3]);
    A[4] = dot2(h, a1.x, A[4]);  A[5] = dot2(h, a1.y, A[5]);
    A[6] = dot2(h, a1.z, A[6]);  A[7] = dot2(h, a1.w, A[7]);
    A[8] = dot2(h, b0.x, A[8]);  A[9] = dot2(h, b0.y, A[9]);
    A[10] = dot2(h, b0.z, A[10]); A[11] = dot2(h, b0.w, A[11]);
    A[12] = dot2(h, b1.x, A[12]); A[13] = dot2(h, b1.y, A[13]);
    A[14] = dot2(h, b1.z, A[14]); A[15] = dot2(h, b1.w, A[15]);
  }
}

__device__ __forceinline__ void fc_emit(const unsigned *__restrict__ h1buf,
                                        const float *__restrict__ fcW,
                                        const float *__restrict__ fcb,
                                        float *__restrict__ out, int sIdx,
                                        int tid, int blk) {
  int q = tid >> 6, l = tid & 63;
  if (q < 3) {
    int o = blk * 3 + q, j = o >> 7, bb = o & 127;
    const unsigned *hc = h1buf + bb;
    const float2 *fw = (const float2 *)(fcW + j * 512);
    float acc = 0.f;
#pragma unroll
    for (int r = 0; r < 4; ++r) {
      int k2 = l + r * 64;
      unsigned d = hc[k2 * 128];
      float2 hf = __half22float2(*(const __half2 *)&d);
      float2 wv = fw[k2];
      acc = fmaf(wv.x, hf.x, acc);
      acc = fmaf(wv.y, hf.y, acc);
    }
#pragma unroll
    for (int off = 32; off; off >>= 1) acc += __shfl_down(acc, off, 64);
    if (l == 0) out[((size_t)bb * 256 + sIdx) * 6 + j] = acc + fcb[j];
  }
}

__global__ __launch_bounds__(512, 2) void seq2seq_kernel(P19 p) {
  const int tid = threadIdx.x;
  const int blk = blockIdx.x;
  const int b = tid & 127;   // batch lane
  const int kh = tid >> 7;   // k-quarter 0..3

  float *ws = p.ws;
  unsigned *flags = (unsigned *)ws;  // 256 flags, 128B-spaced
  unsigned *hpB = (unsigned *)(ws + 8256);
  unsigned *hp0r[2] = {hpB, hpB + 32768};           // h0 parity, [k2][b]
  unsigned *hp1r[2] = {hpB + 65536, hpB + 98304};   // h1 parity
  float *outp = ws + 8256 + 131072;                 // dec seed [j][b] 6*128
  float *srcT = outp + 768;                         // [t][i][b] 256*6*128

  // LDS: 7 matrices x 256 k2 x 2 units x (4 gates half2) = 56 KiB
  __shared__ __align__(16) uint4 wl4[3584];
  __shared__ float4 redux[3][6][128];  // 36 KiB cross-kh partial exchange
  __shared__ float wxe[48], wxd[48], bbuf[40];
  unsigned *wl1 = (unsigned *)wl4;

  {  // ---- stage weights (fp16 pairs) into LDS, once ----
    const float *mats[6] = {p.eWhh0, p.eWih1, p.eWhh1, p.dWhh0, p.dWih1, p.dWhh1};
    for (int e = tid; e < 12288; e += 512) {
      int k2 = e & 255, r = e >> 8;       // r 0..47
      int g = r & 3, uu = (r >> 2) & 1, m = r >> 3;
      const float *row = mats[m] + (size_t)(g * 512 + blk * 2 + uu) * 512;
      wl1[(m * 512 + k2 * 2 + uu) * 4 + g] = packh(row[2 * k2], row[2 * k2 + 1]);
    }
    for (int e = tid; e < 2048; e += 512) {  // W' = dec_Wih0 @ fcW -> slot 6
      int uu = e >> 10, rem = e & 1023, g = rem & 3, k2 = rem >> 2;
      const float *wr = p.dWih0 + (size_t)(g * 512 + blk * 2 + uu) * 6;
      float v0 = 0.f, v1 = 0.f;
#pragma unroll
      for (int i = 0; i < 6; ++i) {
        v0 = fmaf(wr[i], p.fcW[i * 512 + 2 * k2], v0);
        v1 = fmaf(wr[i], p.fcW[i * 512 + 2 * k2 + 1], v1);
      }
      wl1[(6 * 512 + k2 * 2 + uu) * 4 + g] = packh(v0, v1);
    }
    if (tid < 40) {  // fused biases: be0|be1|bd1|b''|bd0
      int f = tid >> 3, k = tid & 7, uu = k >> 2, g = k & 3;
      int r2 = g * 512 + blk * 2 + uu;
      float v;
      if (f == 0) v = p.ebih0[r2] + p.ebhh0[r2];
      else if (f == 1) v = p.ebih1[r2] + p.ebhh1[r2];
      else if (f == 2) v = p.dbih1[r2] + p.dbhh1[r2];
      else {
        v = p.dbih0[r2] + p.dbhh0[r2];
        if (f == 3)
#pragma unroll
          for (int i = 0; i < 6; ++i) v = fmaf(p.dWih0[(size_t)r2 * 6 + i], p.fcb[i], v);
      }
      bbuf[tid] = v;
    } else if (tid >= 64 && tid < 112) {
      int idx = tid - 64, uu = idx / 24, rem = idx % 24, g = rem / 6, i = rem % 6;
      wxe[idx] = p.eWih0[(size_t)(g * 512 + blk * 2 + uu) * 6 + i];
    } else if (tid >= 128 && tid < 176) {
      int idx = tid - 128, uu = idx / 24, rem = idx % 24, g = rem / 6, i = rem % 6;
      wxd[idx] = p.dWih0[(size_t)(g * 512 + blk * 2 + uu) * 6 + i];
    }
  }
  // ---- init: transpose src -> srcT; seed decoder input ----
  for (int e = blk * 512 + tid; e < 196608; e += 131072) {
    int bb = e & 127, rest = e >> 7, i = rest % 6, t = rest / 6;
    srcT[t * 768 + i * 128 + bb] = p.src[((size_t)bb * 256 + t) * 6 + i];
  }
  {
    int g0 = blk * 512 + tid;
    if (g0 < 768) {
      int bb = g0 & 127, i = g0 >> 7;
      outp[i * 128 + bb] = p.src[((size_t)bb * 256 + 255) * 6 + i];
    }
  }
  float c0[2] = {0.f, 0.f}, c1[2] = {0.f, 0.f};
  unsigned gen = 1;
  arrive(flags, gen, tid, blk);
  waitbar(flags, gen, tid);

#define WQ(m) (wl4 + (m) * 512 + kh * 128)
#define HST(buf) ((const unsigned *)(buf) + kh * 8192 + b)
#define RADD(gb, slot) { float4 v = redux[r][slot][b]; \
    G[(gb)] += v.x; G[(gb) + 1] += v.y; G[(gb) + 2] += v.z; G[(gb) + 3] += v.w; }

  // ================= encoder: layer0 & layer1 pipelined (lag 1) ============
  for (int t = 0; t <= 256; ++t) {
    float A16[16], A8[8];
#pragma unroll
    for (int i = 0; i < 16; ++i) A16[i] = 0.f;
#pragma unroll
    for (int i = 0; i < 8; ++i) A8[i] = 0.f;
    dotq2(A16, WQ(0), WQ(1), HST(hp0r[t & 1]));   // eWhh0 + eWih1 share h0
    dotq1(A8, WQ(2), HST(hp1r[(t + 1) & 1]));     // eWhh1 @ h1[t-2]
    if (kh) {
      redux[kh - 1][0][b] = make_float4(A16[0], A16[1], A16[2], A16[3]);
      redux[kh - 1][1][b] = make_float4(A16[4], A16[5], A16[6], A16[7]);
      redux[kh - 1][2][b] = make_float4(A16[8], A16[9], A16[10], A16[11]);
      redux[kh - 1][3][b] = make_float4(A16[12], A16[13], A16[14], A16[15]);
      redux[kh - 1][4][b] = make_float4(A8[0], A8[1], A8[2], A8[3]);
      redux[kh - 1][5][b] = make_float4(A8[4], A8[5], A8[6], A8[7]);
    }
    __syncthreads();
    if (kh == 0) {
      float G[24];
#pragma unroll
      for (int i = 0; i < 16; ++i) G[i] = A16[i];
#pragma unroll
      for (int i = 0; i < 8; ++i) G[16 + i] = A8[i];
#pragma unroll
      for (int r = 0; r < 3; ++r) { RADD(0, 0) RADD(4, 1) RADD(8, 2) RADD(12, 3) RADD(16, 4) RADD(20, 5) }
      if (t < 256) {  // layer0
        float xv[6], h0v[2];
#pragma unroll
        for (int i = 0; i < 6; ++i) xv[i] = srcT[t * 768 + i * 128 + b];
#pragma unroll
        for (int uu = 0; uu < 2; ++uu) {
          float g4[4];
#pragma unroll
          for (int g = 0; g < 4; ++g) {
            float v = G[uu * 4 + g] + bbuf[uu * 4 + g];
#pragma unroll
            for (int i = 0; i < 6; ++i) v = fmaf(wxe[uu * 24 + g * 6 + i], xv[i], v);
            g4[g] = v;
          }
          float ig = sigf(g4[0]), fg = sigf(g4[1]), gg = tanhf(g4[2]), og = sigf(g4[3]);
          c0[uu] = fg * c0[uu] + ig * gg;
          h0v[uu] = og * tanhf(c0[uu]);
        }
        hp0r[(t + 1) & 1][blk * 128 + b] = packh(h0v[0], h0v[1]);
      }
      if (t >= 1) {  // layer1
        float h1v[2];
#pragma unroll
        for (int uu = 0; uu < 2; ++uu) {
          float g4[4];
#pragma unroll
          for (int g = 0; g < 4; ++g)
            g4[g] = G[8 + uu * 4 + g] + G[16 + uu * 4 + g] + bbuf[8 + uu * 4 + g];
          float ig = sigf(g4[0]), fg = sigf(g4[1]), gg = tanhf(g4[2]), og = sigf(g4[3]);
          c1[uu] = fg * c1[uu] + ig * gg;
          h1v[uu] = og * tanhf(c1[uu]);
        }
        hp1r[t & 1][blk * 128 + b] = packh(h1v[0], h1v[1]);
      }
    }
    arrive(flags, ++gen, tid, blk);
    waitbar(flags, gen, tid);
  }
  // enc final: h0 in hp0r[0], h1 in hp1r[0]; c0,c1 in registers.

  // ========== decoder: 2 rounds/step, pre-dots hide barrier waits ==========
  for (int s = 0; s < 256; ++s) {
    // ---- R_A: dec layer0 (+ W'@h1 fused fc; saves Whh1d partial for R_B) --
    float A3[8];
#pragma unroll
    for (int i = 0; i < 8; ++i) A3[i] = 0.f;
    dotq1(A3, WQ(3), HST(hp0r[s & 1]));  // pre-wait: stream 2 barriers old
    if (s) waitbar(flags, gen, tid);
    float AA[16];
#pragma unroll
    for (int i = 0; i < 16; ++i) AA[i] = 0.f;
    if (s == 0) {
      dotq1(AA + 8, WQ(5), HST(hp1r[0]));  // Whh1d partial only
    } else {
      dotq2(AA, WQ(6), WQ(5), HST(hp1r[s & 1]));  // W' + Whh1d share h1
      fc_emit(hp1r[s & 1], p.fcW, p.fcb, p.out, s - 1, tid, blk);
    }
    if (kh) {
      redux[kh - 1][0][b] = make_float4(A3[0], A3[1], A3[2], A3[3]);
      redux[kh - 1][1][b] = make_float4(A3[4], A3[5], A3[6], A3[7]);
      redux[kh - 1][2][b] = make_float4(AA[0], AA[1], AA[2], AA[3]);
      redux[kh - 1][3][b] = make_float4(AA[4], AA[5], AA[6], AA[7]);
    }
    __syncthreads();
    if (kh == 0) {
      float G[8];
#pragma unroll
      for (int i = 0; i < 8; ++i) G[i] = A3[i] + AA[i];
#pragma unroll
      for (int r = 0; r < 3; ++r) { RADD(0, 0) RADD(4, 1) RADD(0, 2) RADD(4, 3) }
      float bq[8];
      if (s == 0) {
        float xv[6];
#pragma unroll
        for (int i = 0; i < 6; ++i) xv[i] = outp[i * 128 + b];
#pragma unroll
        for (int k = 0; k < 8; ++k) {
          int uu = k >> 2, g = k & 3;
          float v = bbuf[32 + k];
#pragma unroll
          for (int i = 0; i < 6; ++i) v = fmaf(wxd[uu * 24 + g * 6 + i], xv[i], v);
          bq[k] = v;
        }
      } else {
#pragma unroll
        for (int k = 0; k < 8; ++k) bq[k] = bbuf[24 + k];
      }
      float h0v[2];
#pragma unroll
      for (int uu = 0; uu < 2; ++uu) {
        float ig = sigf(G[uu * 4 + 0] + bq[uu * 4 + 0]);
        float fg = sigf(G[uu * 4 + 1] + bq[uu * 4 + 1]);
        float gg = tanhf(G[uu * 4 + 2] + bq[uu * 4 + 2]);
        float og = sigf(G[uu * 4 + 3] + bq[uu * 4 + 3]);
        c0[uu] = fg * c0[uu] + ig * gg;
        h0v[uu] = og * tanhf(c0[uu]);
      }
      hp0r[(s + 1) & 1][blk * 128 + b] = packh(h0v[0], h0v[1]);
    }
    arrive(flags, ++gen, tid, blk);
    // ---- R_B: dec layer1 = Whh1d-partial (saved) + Wih1d @ h0[s] (new) ----
    waitbar(flags, gen, tid);
    float A4[8];
#pragma unroll
    for (int i = 0; i < 8; ++i) A4[i] = AA[8 + i];  // saved partial
    dotq1(A4, WQ(4), HST(hp0r[(s + 1) & 1]));
    if (kh) {
      redux[kh - 1][0][b] = make_float4(A4[0], A4[1], A4[2], A4[3]);
      redux[kh - 1][1][b] = make_float4(A4[4], A4[5], A4[6], A4[7]);
    }
    __syncthreads();
    if (kh == 0) {
      float G[8];
#pragma unroll
      for (int i = 0; i < 8; ++i) G[i] = A4[i];
#pragma unroll
      for (int r = 0; r < 3; ++r) { RADD(0, 0) RADD(4, 1) }
      float h1v[2];
#pragma unroll
      for (int uu = 0; uu < 2; ++uu) {
        float ig = sigf(G[uu * 4 + 0] + bbuf[16 + uu * 4 + 0]);
        float fg = sigf(G[uu * 4 + 1] + bbuf[16 + uu * 4 + 1]);
        float gg = tanhf(G[uu * 4 + 2] + bbuf[16 + uu * 4 + 2]);
        float og = sigf(G[uu * 4 + 3] + bbuf[16 + uu * 4 + 3]);
        c1[uu] = fg * c1[uu] + ig * gg;
        h1v[uu] = og * tanhf(c1[uu]);
      }
      hp1r[(s + 1) & 1][blk * 128 + b] = packh(h1v[0], h1v[1]);
    }
    arrive(flags, ++gen, tid, blk);
  }
  waitbar(flags, gen, tid);
  fc_emit(hp1r[0], p.fcW, p.fcb, p.out, 255, tid, blk);  // tail out[255]
}

extern "C" void kernel_launch(void *const *d_in, const int *in_sizes, int n_in,
                              void *d_out, int out_size, void *d_ws, size_t ws_size,
                              hipStream_t stream) {
  (void)in_sizes; (void)n_in; (void)out_size; (void)ws_size;
  P19 p;
  p.src = (const float *)d_in[0];
  p.eWih0 = (const float *)d_in[1];  p.eWhh0 = (const float *)d_in[2];
  p.ebih0 = (const float *)d_in[3];  p.ebhh0 = (const float *)d_in[4];
  p.eWih1 = (const float *)d_in[5];  p.eWhh1 = (const float *)d_in[6];
  p.ebih1 = (const float *)d_in[7];  p.ebhh1 = (const float *)d_in[8];
  p.dWih0 = (const float *)d_in[9];  p.dWhh0 = (const float *)d_in[10];
  p.dbih0 = (const float *)d_in[11]; p.dbhh0 = (const float *)d_in[12];
  p.dWih1 = (const float *)d_in[13]; p.dWhh1 = (const float *)d_in[14];
  p.dbih1 = (const float *)d_in[15]; p.dbhh1 = (const float *)d_in[16];
  p.fcW = (const float *)d_in[17];   p.fcb = (const float *)d_in[18];
  p.out = (float *)d_out;
  p.ws = (float *)d_ws;

  // zero flags + 4 packed-h parity buffers (outp/srcT written by kernel init)
  hipMemsetAsync(d_ws, 0, (size_t)(8256 + 4 * 32768) * sizeof(float), stream);
  seq2seq_kernel<<<dim3(256), dim3(512), 0, stream>>>(p);
}

// Round 8
// 28675.430 us; speedup vs baseline: 3.9532x; 3.9532x over previous
//
#include <hip/hip_runtime.h>
#include <hip/hip_fp16.h>

// ---------------- parameters (all inputs fp32; output fp32) ----------------
struct P19 {
  const float *src;
  const float *eWih0, *eWhh0, *ebih0, *ebhh0;
  const float *eWih1, *eWhh1, *ebih1, *ebhh1;
  const float *dWih0, *dWhh0, *dbih0, *dbhh0;
  const float *dWih1, *dWhh1, *dbih1, *dbhh1;
  const float *fcW, *fcb;
  float *out;
  float *ws;
};

typedef _Float16 h2v __attribute__((ext_vector_type(2)));

__device__ __forceinline__ float sigf(float x) { return 1.f / (1.f + __expf(-x)); }

__device__ __forceinline__ unsigned packh(float a, float b2) {
  __half2 h2 = __floats2half2_rn(a, b2);
  return *(const unsigned *)&h2;
}

__device__ __forceinline__ float dot2(unsigned h, unsigned w, float acc) {
#if __has_builtin(__builtin_amdgcn_fdot2)
  return __builtin_amdgcn_fdot2(*(h2v *)&h, *(h2v *)&w, acc, false);
#else
  float2 hf = __half22float2(*(const __half2 *)&h);
  float2 wf = __half22float2(*(const __half2 *)&w);
  return fmaf(hf.x, wf.x, fmaf(hf.y, wf.y, acc));
#endif
}

// ---- split-phase distributed-flag grid barrier (1 block/CU by LDS>80KB) ---
__device__ __forceinline__ void arrive(unsigned *flags, unsigned gen, int tid, int blk) {
  __syncthreads();  // drains all waves' stores before flag
  if (tid == 0) {
    __threadfence();  // release: push h writes to coherence point
    __hip_atomic_store(flags + blk * 32, gen, __ATOMIC_RELEASE, __HIP_MEMORY_SCOPE_AGENT);
  }
}
__device__ __forceinline__ void waitbar(unsigned *flags, unsigned gen, int tid) {
  if (tid < 256) {
    unsigned *f = flags + tid * 32;
    int g = 0;
    while (__hip_atomic_load(f, __ATOMIC_RELAXED, __HIP_MEMORY_SCOPE_AGENT) < gen) {
      __builtin_amdgcn_s_sleep(4);
      if (++g > (1 << 16)) break;  // safety: never deadlock the bench
    }
  }
  __syncthreads();
  if (tid == 0) __threadfence();  // acquire: invalidate caches before reads
  __syncthreads();
}

// ---- quarter-dots: thread covers BOTH units (8 gate-rows) over 64 k2 ----
// Double-buffered 16-dword chunks (register-resident; fits 256-VGPR budget).
// weights per k2: 2x uint4 (unit0 g0..g3, unit1 g0..g3), same-addr broadcast.
__device__ __forceinline__ void dotq1(float *A, const uint4 *__restrict__ wq,
                                      const unsigned *__restrict__ hq) {
  unsigned ca[16], cb[16];
#pragma unroll
  for (int c = 0; c < 16; ++c) ca[c] = hq[c * 128];
  for (int j = 0; j < 4; j += 2) {
#pragma unroll
    for (int c = 0; c < 16; ++c) cb[c] = hq[((j + 1) * 16 + c) * 128];
#pragma unroll
    for (int c = 0; c < 16; ++c) {
      int k2 = j * 16 + c;
      uint4 w0 = wq[k2 * 2], w1 = wq[k2 * 2 + 1];
      unsigned h = ca[c];
      A[0] = dot2(h, w0.x, A[0]); A[1] = dot2(h, w0.y, A[1]);
      A[2] = dot2(h, w0.z, A[2]); A[3] = dot2(h, w0.w, A[3]);
      A[4] = dot2(h, w1.x, A[4]); A[5] = dot2(h, w1.y, A[5]);
      A[6] = dot2(h, w1.z, A[6]); A[7] = dot2(h, w1.w, A[7]);
    }
#pragma unroll
    for (int c = 0; c < 16; ++c) ca[c] = hq[((((j + 2) & 3)) * 16 + c) * 128];
#pragma unroll
    for (int c = 0; c < 16; ++c) {
      int k2 = (j + 1) * 16 + c;
      uint4 w0 = wq[k2 * 2], w1 = wq[k2 * 2 + 1];
      unsigned h = cb[c];
      A[0] = dot2(h, w0.x, A[0]); A[1] = dot2(h, w0.y, A[1]);
      A[2] = dot2(h, w0.z, A[2]); A[3] = dot2(h, w0.w, A[3]);
      A[4] = dot2(h, w1.x, A[4]); A[5] = dot2(h, w1.y, A[5]);
      A[6] = dot2(h, w1.z, A[6]); A[7] = dot2(h, w1.w, A[7]);
    }
  }
}
__device__ __forceinline__ void dotq2(float *A, const uint4 *__restrict__ w0q,
                                      const uint4 *__restrict__ w1q,
                                      const unsigned *__restrict__ hq) {
  unsigned ca[16], cb[16];
#pragma unroll
  for (int c = 0; c < 16; ++c) ca[c] = hq[c * 128];
  for (int j = 0; j < 4; j += 2) {
#pragma unroll
    for (int c = 0; c < 16; ++c) cb[c] = hq[((j + 1) * 16 + c) * 128];
#pragma unroll
    for (int c = 0; c < 16; ++c) {
      int k2 = j * 16 + c;
      uint4 a0 = w0q[k2 * 2], a1 = w0q[k2 * 2 + 1];
      uint4 b0 = w1q[k2 * 2], b1 = w1q[k2 * 2 + 1];
      unsigned h = ca[c];
      A[0] = dot2(h, a0.x, A[0]);   A[1] = dot2(h, a0.y, A[1]);
      A[2] = dot2(h, a0.z, A[2]);   A[3] = dot2(h, a0.w, A[3]);
      A[4] = dot2(h, a1.x, A[4]);   A[5] = dot2(h, a1.y, A[5]);
      A[6] = dot2(h, a1.z, A[6]);   A[7] = dot2(h, a1.w, A[7]);
      A[8] = dot2(h, b0.x, A[8]);   A[9] = dot2(h, b0.y, A[9]);
      A[10] = dot2(h, b0.z, A[10]); A[11] = dot2(h, b0.w, A[11]);
      A[12] = dot2(h, b1.x, A[12]); A[13] = dot2(h, b1.y, A[13]);
      A[14] = dot2(h, b1.z, A[14]); A[15] = dot2(h, b1.w, A[15]);
    }
#pragma unroll
    for (int c = 0; c < 16; ++c) ca[c] = hq[((((j + 2) & 3)) * 16 + c) * 128];
#pragma unroll
    for (int c = 0; c < 16; ++c) {
      int k2 = (j + 1) * 16 + c;
      uint4 a0 = w0q[k2 * 2], a1 = w0q[k2 * 2 + 1];
      uint4 b0 = w1q[k2 * 2], b1 = w1q[k2 * 2 + 1];
      unsigned h = cb[c];
      A[0] = dot2(h, a0.x, A[0]);   A[1] = dot2(h, a0.y, A[1]);
      A[2] = dot2(h, a0.z, A[2]);   A[3] = dot2(h, a0.w, A[3]);
      A[4] = dot2(h, a1.x, A[4]);   A[5] = dot2(h, a1.y, A[5]);
      A[6] = dot2(h, a1.z, A[6]);   A[7] = dot2(h, a1.w, A[7]);
      A[8] = dot2(h, b0.x, A[8]);   A[9] = dot2(h, b0.y, A[9]);
      A[10] = dot2(h, b0.z, A[10]); A[11] = dot2(h, b0.w, A[11]);
      A[12] = dot2(h, b1.x, A[12]); A[13] = dot2(h, b1.y, A[13]);
      A[14] = dot2(h, b1.z, A[14]); A[15] = dot2(h, b1.w, A[15]);
    }
  }
}

__device__ __forceinline__ void fc_emit(const unsigned *__restrict__ h1buf,
                                        const float *__restrict__ fcW,
                                        const float *__restrict__ fcb,
                                        float *__restrict__ out, int sIdx,
                                        int tid, int blk) {
  int q = tid >> 6, l = tid & 63;
  if (q < 3) {
    int o = blk * 3 + q, j = o >> 7, bb = o & 127;
    const unsigned *hc = h1buf + bb;
    const float2 *fw = (const float2 *)(fcW + j * 512);
    float acc = 0.f;
#pragma unroll
    for (int r = 0; r < 4; ++r) {
      int k2 = l + r * 64;
      unsigned d = hc[k2 * 128];
      float2 hf = __half22float2(*(const __half2 *)&d);
      float2 wv = fw[k2];
      acc = fmaf(wv.x, hf.x, acc);
      acc = fmaf(wv.y, hf.y, acc);
    }
#pragma unroll
    for (int off = 32; off; off >>= 1) acc += __shfl_down(acc, off, 64);
    if (l == 0) out[((size_t)bb * 256 + sIdx) * 6 + j] = acc + fcb[j];
  }
}

// NOTE: min-waves arg MUST be 1. LDS (93KB) already forces 1 block/CU; a
// larger value only caps VGPRs (r7: cap 128 -> ca[] spilled -> 290GB scratch).
__global__ __launch_bounds__(512, 1) void seq2seq_kernel(P19 p) {
  const int tid = threadIdx.x;
  const int blk = blockIdx.x;
  const int b = tid & 127;   // batch lane
  const int kh = tid >> 7;   // k-quarter 0..3

  float *ws = p.ws;
  unsigned *flags = (unsigned *)ws;  // 256 flags, 128B-spaced
  unsigned *hpB = (unsigned *)(ws + 8256);
  unsigned *hp0r[2] = {hpB, hpB + 32768};           // h0 parity, [k2][b]
  unsigned *hp1r[2] = {hpB + 65536, hpB + 98304};   // h1 parity
  float *outp = ws + 8256 + 131072;                 // dec seed [j][b] 6*128
  float *srcT = outp + 768;                         // [t][i][b] 256*6*128

  // LDS: 7 matrices x 256 k2 x 2 units x (4 gates half2) = 56 KiB
  __shared__ __align__(16) uint4 wl4[3584];
  __shared__ float4 redux[3][6][128];  // 36 KiB cross-kh partial exchange
  __shared__ float wxe[48], wxd[48], bbuf[40];
  unsigned *wl1 = (unsigned *)wl4;

  {  // ---- stage weights (fp16 pairs) into LDS, once ----
    const float *mats[6] = {p.eWhh0, p.eWih1, p.eWhh1, p.dWhh0, p.dWih1, p.dWhh1};
    for (int e = tid; e < 12288; e += 512) {
      int k2 = e & 255, r = e >> 8;       // r 0..47
      int g = r & 3, uu = (r >> 2) & 1, m = r >> 3;
      const float *row = mats[m] + (size_t)(g * 512 + blk * 2 + uu) * 512;
      wl1[(m * 512 + k2 * 2 + uu) * 4 + g] = packh(row[2 * k2], row[2 * k2 + 1]);
    }
    for (int e = tid; e < 2048; e += 512) {  // W' = dec_Wih0 @ fcW -> slot 6
      int uu = e >> 10, rem = e & 1023, g = rem & 3, k2 = rem >> 2;
      const float *wr = p.dWih0 + (size_t)(g * 512 + blk * 2 + uu) * 6;
      float v0 = 0.f, v1 = 0.f;
#pragma unroll
      for (int i = 0; i < 6; ++i) {
        v0 = fmaf(wr[i], p.fcW[i * 512 + 2 * k2], v0);
        v1 = fmaf(wr[i], p.fcW[i * 512 + 2 * k2 + 1], v1);
      }
      wl1[(6 * 512 + k2 * 2 + uu) * 4 + g] = packh(v0, v1);
    }
    if (tid < 40) {  // fused biases: be0|be1|bd1|b''|bd0
      int f = tid >> 3, k = tid & 7, uu = k >> 2, g = k & 3;
      int r2 = g * 512 + blk * 2 + uu;
      float v;
      if (f == 0) v = p.ebih0[r2] + p.ebhh0[r2];
      else if (f == 1) v = p.ebih1[r2] + p.ebhh1[r2];
      else if (f == 2) v = p.dbih1[r2] + p.dbhh1[r2];
      else {
        v = p.dbih0[r2] + p.dbhh0[r2];
        if (f == 3)
#pragma unroll
          for (int i = 0; i < 6; ++i) v = fmaf(p.dWih0[(size_t)r2 * 6 + i], p.fcb[i], v);
      }
      bbuf[tid] = v;
    } else if (tid >= 64 && tid < 112) {
      int idx = tid - 64, uu = idx / 24, rem = idx % 24, g = rem / 6, i = rem % 6;
      wxe[idx] = p.eWih0[(size_t)(g * 512 + blk * 2 + uu) * 6 + i];
    } else if (tid >= 128 && tid < 176) {
      int idx = tid - 128, uu = idx / 24, rem = idx % 24, g = rem / 6, i = rem % 6;
      wxd[idx] = p.dWih0[(size_t)(g * 512 + blk * 2 + uu) * 6 + i];
    }
  }
  // ---- init: transpose src -> srcT; seed decoder input ----
  for (int e = blk * 512 + tid; e < 196608; e += 131072) {
    int bb = e & 127, rest = e >> 7, i = rest % 6, t = rest / 6;
    srcT[t * 768 + i * 128 + bb] = p.src[((size_t)bb * 256 + t) * 6 + i];
  }
  {
    int g0 = blk * 512 + tid;
    if (g0 < 768) {
      int bb = g0 & 127, i = g0 >> 7;
      outp[i * 128 + bb] = p.src[((size_t)bb * 256 + 255) * 6 + i];
    }
  }
  float c0[2] = {0.f, 0.f}, c1[2] = {0.f, 0.f};
  unsigned gen = 1;
  arrive(flags, gen, tid, blk);
  waitbar(flags, gen, tid);

#define WQ(m) (wl4 + (m) * 512 + kh * 128)
#define HST(buf) ((const unsigned *)(buf) + kh * 8192 + b)
#define RADD(gb, slot) { float4 v = redux[r][slot][b]; \
    G[(gb)] += v.x; G[(gb) + 1] += v.y; G[(gb) + 2] += v.z; G[(gb) + 3] += v.w; }

  // ================= encoder: layer0 & layer1 pipelined (lag 1) ============
  for (int t = 0; t <= 256; ++t) {
    float A16[16], A8[8];
#pragma unroll
    for (int i = 0; i < 16; ++i) A16[i] = 0.f;
#pragma unroll
    for (int i = 0; i < 8; ++i) A8[i] = 0.f;
    dotq2(A16, WQ(0), WQ(1), HST(hp0r[t & 1]));   // eWhh0 + eWih1 share h0
    dotq1(A8, WQ(2), HST(hp1r[(t + 1) & 1]));     // eWhh1 @ h1[t-2]
    if (kh) {
      redux[kh - 1][0][b] = make_float4(A16[0], A16[1], A16[2], A16[3]);
      redux[kh - 1][1][b] = make_float4(A16[4], A16[5], A16[6], A16[7]);
      redux[kh - 1][2][b] = make_float4(A16[8], A16[9], A16[10], A16[11]);
      redux[kh - 1][3][b] = make_float4(A16[12], A16[13], A16[14], A16[15]);
      redux[kh - 1][4][b] = make_float4(A8[0], A8[1], A8[2], A8[3]);
      redux[kh - 1][5][b] = make_float4(A8[4], A8[5], A8[6], A8[7]);
    }
    __syncthreads();
    if (kh == 0) {
      float G[24];
#pragma unroll
      for (int i = 0; i < 16; ++i) G[i] = A16[i];
#pragma unroll
      for (int i = 0; i < 8; ++i) G[16 + i] = A8[i];
#pragma unroll
      for (int r = 0; r < 3; ++r) { RADD(0, 0) RADD(4, 1) RADD(8, 2) RADD(12, 3) RADD(16, 4) RADD(20, 5) }
      if (t < 256) {  // layer0
        float xv[6], h0v[2];
#pragma unroll
        for (int i = 0; i < 6; ++i) xv[i] = srcT[t * 768 + i * 128 + b];
#pragma unroll
        for (int uu = 0; uu < 2; ++uu) {
          float g4[4];
#pragma unroll
          for (int g = 0; g < 4; ++g) {
            float v = G[uu * 4 + g] + bbuf[uu * 4 + g];
#pragma unroll
            for (int i = 0; i < 6; ++i) v = fmaf(wxe[uu * 24 + g * 6 + i], xv[i], v);
            g4[g] = v;
          }
          float ig = sigf(g4[0]), fg = sigf(g4[1]), gg = tanhf(g4[2]), og = sigf(g4[3]);
          c0[uu] = fg * c0[uu] + ig * gg;
          h0v[uu] = og * tanhf(c0[uu]);
        }
        hp0r[(t + 1) & 1][blk * 128 + b] = packh(h0v[0], h0v[1]);
      }
      if (t >= 1) {  // layer1
        float h1v[2];
#pragma unroll
        for (int uu = 0; uu < 2; ++uu) {
          float g4[4];
#pragma unroll
          for (int g = 0; g < 4; ++g)
            g4[g] = G[8 + uu * 4 + g] + G[16 + uu * 4 + g] + bbuf[8 + uu * 4 + g];
          float ig = sigf(g4[0]), fg = sigf(g4[1]), gg = tanhf(g4[2]), og = sigf(g4[3]);
          c1[uu] = fg * c1[uu] + ig * gg;
          h1v[uu] = og * tanhf(c1[uu]);
        }
        hp1r[t & 1][blk * 128 + b] = packh(h1v[0], h1v[1]);
      }
    }
    arrive(flags, ++gen, tid, blk);
    waitbar(flags, gen, tid);
  }
  // enc final: h0 in hp0r[0], h1 in hp1r[0]; c0,c1 in registers.

  // ========== decoder: 2 rounds/step, pre-dots hide barrier waits ==========
  for (int s = 0; s < 256; ++s) {
    // ---- R_A: dec layer0 (+ W'@h1 fused fc; saves Whh1d partial for R_B) --
    float A3[8];
#pragma unroll
    for (int i = 0; i < 8; ++i) A3[i] = 0.f;
    dotq1(A3, WQ(3), HST(hp0r[s & 1]));  // pre-wait: stream synced 1 gen ago
    if (s) waitbar(flags, gen, tid);
    float AA[16];
#pragma unroll
    for (int i = 0; i < 16; ++i) AA[i] = 0.f;
    if (s == 0) {
      dotq1(AA + 8, WQ(5), HST(hp1r[0]));  // Whh1d partial only
    } else {
      dotq2(AA, WQ(6), WQ(5), HST(hp1r[s & 1]));  // W' + Whh1d share h1
      fc_emit(hp1r[s & 1], p.fcW, p.fcb, p.out, s - 1, tid, blk);
    }
    if (kh) {
      redux[kh - 1][0][b] = make_float4(A3[0], A3[1], A3[2], A3[3]);
      redux[kh - 1][1][b] = make_float4(A3[4], A3[5], A3[6], A3[7]);
      redux[kh - 1][2][b] = make_float4(AA[0], AA[1], AA[2], AA[3]);
      redux[kh - 1][3][b] = make_float4(AA[4], AA[5], AA[6], AA[7]);
    }
    __syncthreads();
    if (kh == 0) {
      float G[8];
#pragma unroll
      for (int i = 0; i < 8; ++i) G[i] = A3[i] + AA[i];
#pragma unroll
      for (int r = 0; r < 3; ++r) { RADD(0, 0) RADD(4, 1) RADD(0, 2) RADD(4, 3) }
      float bq[8];
      if (s == 0) {
        float xv[6];
#pragma unroll
        for (int i = 0; i < 6; ++i) xv[i] = outp[i * 128 + b];
#pragma unroll
        for (int k = 0; k < 8; ++k) {
          int uu = k >> 2, g = k & 3;
          float v = bbuf[32 + k];
#pragma unroll
          for (int i = 0; i < 6; ++i) v = fmaf(wxd[uu * 24 + g * 6 + i], xv[i], v);
          bq[k] = v;
        }
      } else {
#pragma unroll
        for (int k = 0; k < 8; ++k) bq[k] = bbuf[24 + k];
      }
      float h0v[2];
#pragma unroll
      for (int uu = 0; uu < 2; ++uu) {
        float ig = sigf(G[uu * 4 + 0] + bq[uu * 4 + 0]);
        float fg = sigf(G[uu * 4 + 1] + bq[uu * 4 + 1]);
        float gg = tanhf(G[uu * 4 + 2] + bq[uu * 4 + 2]);
        float og = sigf(G[uu * 4 + 3] + bq[uu * 4 + 3]);
        c0[uu] = fg * c0[uu] + ig * gg;
        h0v[uu] = og * tanhf(c0[uu]);
      }
      hp0r[(s + 1) & 1][blk * 128 + b] = packh(h0v[0], h0v[1]);
    }
    arrive(flags, ++gen, tid, blk);
    // ---- R_B: dec layer1 = Whh1d-partial (saved) + Wih1d @ h0[s] (new) ----
    waitbar(flags, gen, tid);
    float A4[8];
#pragma unroll
    for (int i = 0; i < 8; ++i) A4[i] = AA[8 + i];  // saved partial
    dotq1(A4, WQ(4), HST(hp0r[(s + 1) & 1]));
    if (kh) {
      redux[kh - 1][0][b] = make_float4(A4[0], A4[1], A4[2], A4[3]);
      redux[kh - 1][1][b] = make_float4(A4[4], A4[5], A4[6], A4[7]);
    }
    __syncthreads();
    if (kh == 0) {
      float G[8];
#pragma unroll
      for (int i = 0; i < 8; ++i) G[i] = A4[i];
#pragma unroll
      for (int r = 0; r < 3; ++r) { RADD(0, 0) RADD(4, 1) }
      float h1v[2];
#pragma unroll
      for (int uu = 0; uu < 2; ++uu) {
        float ig = sigf(G[uu * 4 + 0] + bbuf[16 + uu * 4 + 0]);
        float fg = sigf(G[uu * 4 + 1] + bbuf[16 + uu * 4 + 1]);
        float gg = tanhf(G[uu * 4 + 2] + bbuf[16 + uu * 4 + 2]);
        float og = sigf(G[uu * 4 + 3] + bbuf[16 + uu * 4 + 3]);
        c1[uu] = fg * c1[uu] + ig * gg;
        h1v[uu] = og * tanhf(c1[uu]);
      }
      hp1r[(s + 1) & 1][blk * 128 + b] = packh(h1v[0], h1v[1]);
    }
    arrive(flags, ++gen, tid, blk);
  }
  waitbar(flags, gen, tid);
  fc_emit(hp1r[0], p.fcW, p.fcb, p.out, 255, tid, blk);  // tail out[255]
}

extern "C" void kernel_launch(void *const *d_in, const int *in_sizes, int n_in,
                              void *d_out, int out_size, void *d_ws, size_t ws_size,
                              hipStream_t stream) {
  (void)in_sizes; (void)n_in; (void)out_size; (void)ws_size;
  P19 p;
  p.src = (const float *)d_in[0];
  p.eWih0 = (const float *)d_in[1];  p.eWhh0 = (const float *)d_in[2];
  p.ebih0 = (const float *)d_in[3];  p.ebhh0 = (const float *)d_in[4];
  p.eWih1 = (const float *)d_in[5];  p.eWhh1 = (const float *)d_in[6];
  p.ebih1 = (const float *)d_in[7];  p.ebhh1 = (const float *)d_in[8];
  p.dWih0 = (const float *)d_in[9];  p.dWhh0 = (const float *)d_in[10];
  p.dbih0 = (const float *)d_in[11]; p.dbhh0 = (const float *)d_in[12];
  p.dWih1 = (const float *)d_in[13]; p.dWhh1 = (const float *)d_in[14];
  p.dbih1 = (const float *)d_in[15]; p.dbhh1 = (const float *)d_in[16];
  p.fcW = (const float *)d_in[17];   p.fcb = (const float *)d_in[18];
  p.out = (float *)d_out;
  p.ws = (float *)d_ws;

  // zero flags + 4 packed-h parity buffers (outp/srcT written by kernel init)
  hipMemsetAsync(d_ws, 0, (size_t)(8256 + 4 * 32768) * sizeof(float), stream);
  seq2seq_kernel<<<dim3(256), dim3(512), 0, stream>>>(p);
}

// Round 9
// 22883.391 us; speedup vs baseline: 4.9538x; 1.2531x over previous
//
#include <hip/hip_runtime.h>
#include <hip/hip_fp16.h>

// ---------------- parameters (all inputs fp32; output fp32) ----------------
struct P19 {
  const float *src;
  const float *eWih0, *eWhh0, *ebih0, *ebhh0;
  const float *eWih1, *eWhh1, *ebih1, *ebhh1;
  const float *dWih0, *dWhh0, *dbih0, *dbhh0;
  const float *dWih1, *dWhh1, *dbih1, *dbhh1;
  const float *fcW, *fcb;
  float *out;
  float *ws;
};

typedef _Float16 h2v __attribute__((ext_vector_type(2)));

__device__ __forceinline__ float sigf(float x) { return 1.f / (1.f + __expf(-x)); }

__device__ __forceinline__ unsigned packh(float a, float b2) {
  __half2 h2 = __floats2half2_rn(a, b2);
  return *(const unsigned *)&h2;
}

__device__ __forceinline__ float dot2(unsigned h, unsigned w, float acc) {
#if __has_builtin(__builtin_amdgcn_fdot2)
  return __builtin_amdgcn_fdot2(*(h2v *)&h, *(h2v *)&w, acc, false);
#else
  float2 hf = __half22float2(*(const __half2 *)&h);
  float2 wf = __half22float2(*(const __half2 *)&w);
  return fmaf(hf.x, wf.x, fmaf(hf.y, wf.y, acc));
#endif
}

// ---- split-phase distributed-flag grid barrier (grid == 256 == #CUs) ------
__device__ __forceinline__ void arrive(unsigned *flags, unsigned gen, int tid, int blk) {
  __syncthreads();  // drains all waves' stores before flag
  if (tid == 0) {
    __threadfence();  // release: push h writes to coherence point
    __hip_atomic_store(flags + blk * 32, gen, __ATOMIC_RELEASE, __HIP_MEMORY_SCOPE_AGENT);
  }
}
__device__ __forceinline__ void waitbar(unsigned *flags, unsigned gen, int tid) {
  {
    unsigned *f = flags + tid * 32;
    int g = 0;
    while (__hip_atomic_load(f, __ATOMIC_RELAXED, __HIP_MEMORY_SCOPE_AGENT) < gen) {
      __builtin_amdgcn_s_sleep(4);
      if (++g > (1 << 16)) break;  // safety: never deadlock the bench
    }
  }
  __syncthreads();
  if (tid == 0) __threadfence();  // acquire: invalidate caches before reads
  __syncthreads();
}

// ---- half-dots: thread covers BOTH units (8 gate-rows) over 128 k2 -------
// Double-buffered 32-dword chunks. 256-thread blocks -> 1 wave/SIMD -> full
// 512-VGPR budget (r7/r8 lesson: 512-thr blocks cap at 128 VGPR -> spills).
// weights per k2: 2x uint4 (unit0 g0..g3, unit1 g0..g3), same-addr broadcast.
__device__ __forceinline__ void dotq1(float *A, const uint4 *__restrict__ wq,
                                      const unsigned *__restrict__ hq) {
  unsigned ca[32], cb[32];
#pragma unroll
  for (int c = 0; c < 32; ++c) ca[c] = hq[c * 128];
  for (int j = 0; j < 4; j += 2) {
#pragma unroll
    for (int c = 0; c < 32; ++c) cb[c] = hq[((j + 1) * 32 + c) * 128];
#pragma unroll
    for (int c = 0; c < 32; ++c) {
      int k2 = j * 32 + c;
      uint4 w0 = wq[k2 * 2], w1 = wq[k2 * 2 + 1];
      unsigned h = ca[c];
      A[0] = dot2(h, w0.x, A[0]); A[1] = dot2(h, w0.y, A[1]);
      A[2] = dot2(h, w0.z, A[2]); A[3] = dot2(h, w0.w, A[3]);
      A[4] = dot2(h, w1.x, A[4]); A[5] = dot2(h, w1.y, A[5]);
      A[6] = dot2(h, w1.z, A[6]); A[7] = dot2(h, w1.w, A[7]);
    }
#pragma unroll
    for (int c = 0; c < 32; ++c) ca[c] = hq[((((j + 2) & 3)) * 32 + c) * 128];
#pragma unroll
    for (int c = 0; c < 32; ++c) {
      int k2 = (j + 1) * 32 + c;
      uint4 w0 = wq[k2 * 2], w1 = wq[k2 * 2 + 1];
      unsigned h = cb[c];
      A[0] = dot2(h, w0.x, A[0]); A[1] = dot2(h, w0.y, A[1]);
      A[2] = dot2(h, w0.z, A[2]); A[3] = dot2(h, w0.w, A[3]);
      A[4] = dot2(h, w1.x, A[4]); A[5] = dot2(h, w1.y, A[5]);
      A[6] = dot2(h, w1.z, A[6]); A[7] = dot2(h, w1.w, A[7]);
    }
  }
}
__device__ __forceinline__ void dotq2(float *A, const uint4 *__restrict__ w0q,
                                      const uint4 *__restrict__ w1q,
                                      const unsigned *__restrict__ hq) {
  unsigned ca[32], cb[32];
#pragma unroll
  for (int c = 0; c < 32; ++c) ca[c] = hq[c * 128];
  for (int j = 0; j < 4; j += 2) {
#pragma unroll
    for (int c = 0; c < 32; ++c) cb[c] = hq[((j + 1) * 32 + c) * 128];
#pragma unroll
    for (int c = 0; c < 32; ++c) {
      int k2 = j * 32 + c;
      uint4 a0 = w0q[k2 * 2], a1 = w0q[k2 * 2 + 1];
      uint4 b0 = w1q[k2 * 2], b1 = w1q[k2 * 2 + 1];
      unsigned h = ca[c];
      A[0] = dot2(h, a0.x, A[0]);   A[1] = dot2(h, a0.y, A[1]);
      A[2] = dot2(h, a0.z, A[2]);   A[3] = dot2(h, a0.w, A[3]);
      A[4] = dot2(h, a1.x, A[4]);   A[5] = dot2(h, a1.y, A[5]);
      A[6] = dot2(h, a1.z, A[6]);   A[7] = dot2(h, a1.w, A[7]);
      A[8] = dot2(h, b0.x, A[8]);   A[9] = dot2(h, b0.y, A[9]);
      A[10] = dot2(h, b0.z, A[10]); A[11] = dot2(h, b0.w, A[11]);
      A[12] = dot2(h, b1.x, A[12]); A[13] = dot2(h, b1.y, A[13]);
      A[14] = dot2(h, b1.z, A[14]); A[15] = dot2(h, b1.w, A[15]);
    }
#pragma unroll
    for (int c = 0; c < 32; ++c) ca[c] = hq[((((j + 2) & 3)) * 32 + c) * 128];
#pragma unroll
    for (int c = 0; c < 32; ++c) {
      int k2 = (j + 1) * 32 + c;
      uint4 a0 = w0q[k2 * 2], a1 = w0q[k2 * 2 + 1];
      uint4 b0 = w1q[k2 * 2], b1 = w1q[k2 * 2 + 1];
      unsigned h = cb[c];
      A[0] = dot2(h, a0.x, A[0]);   A[1] = dot2(h, a0.y, A[1]);
      A[2] = dot2(h, a0.z, A[2]);   A[3] = dot2(h, a0.w, A[3]);
      A[4] = dot2(h, a1.x, A[4]);   A[5] = dot2(h, a1.y, A[5]);
      A[6] = dot2(h, a1.z, A[6]);   A[7] = dot2(h, a1.w, A[7]);
      A[8] = dot2(h, b0.x, A[8]);   A[9] = dot2(h, b0.y, A[9]);
      A[10] = dot2(h, b0.z, A[10]); A[11] = dot2(h, b0.w, A[11]);
      A[12] = dot2(h, b1.x, A[12]); A[13] = dot2(h, b1.y, A[13]);
      A[14] = dot2(h, b1.z, A[14]); A[15] = dot2(h, b1.w, A[15]);
    }
  }
}

__device__ __forceinline__ void fc_emit(const unsigned *__restrict__ h1buf,
                                        const float *__restrict__ fcW,
                                        const float *__restrict__ fcb,
                                        float *__restrict__ out, int sIdx,
                                        int tid, int blk) {
  int q = tid >> 6, l = tid & 63;
  if (q < 3) {
    int o = blk * 3 + q, j = o >> 7, bb = o & 127;
    const unsigned *hc = h1buf + bb;
    const float2 *fw = (const float2 *)(fcW + j * 512);
    float acc = 0.f;
#pragma unroll
    for (int r = 0; r < 4; ++r) {
      int k2 = l + r * 64;
      unsigned d = hc[k2 * 128];
      float2 hf = __half22float2(*(const __half2 *)&d);
      float2 wv = fw[k2];
      acc = fmaf(wv.x, hf.x, acc);
      acc = fmaf(wv.y, hf.y, acc);
    }
#pragma unroll
    for (int off = 32; off; off >>= 1) acc += __shfl_down(acc, off, 64);
    if (l == 0) out[((size_t)bb * 256 + sIdx) * 6 + j] = acc + fcb[j];
  }
}

__global__ __launch_bounds__(256, 1) void seq2seq_kernel(P19 p) {
  const int tid = threadIdx.x;
  const int blk = blockIdx.x;
  const int b = tid & 127;   // batch lane
  const int kh = tid >> 7;   // k-half 0..1

  float *ws = p.ws;
  unsigned *flags = (unsigned *)ws;  // 256 flags, 128B-spaced
  unsigned *hpB = (unsigned *)(ws + 8256);
  unsigned *hp0r[2] = {hpB, hpB + 32768};           // h0 parity, [k2][b]
  unsigned *hp1r[2] = {hpB + 65536, hpB + 98304};   // h1 parity
  float *outp = ws + 8256 + 131072;                 // dec seed [j][b] 6*128
  float *srcT = outp + 768;                         // [t][i][b] 256*6*128

  // LDS: 7 matrices x 256 k2 x 2 units x (4 gates half2) = 56 KiB
  __shared__ __align__(16) uint4 wl4[3584];
  __shared__ float4 redux[6][128];  // 12 KiB: kh=1 partial-dot exchange
  __shared__ float wxe[48], wxd[48], bbuf[40];
  unsigned *wl1 = (unsigned *)wl4;

  {  // ---- stage weights (fp16 pairs) into LDS, once ----
    const float *mats[6] = {p.eWhh0, p.eWih1, p.eWhh1, p.dWhh0, p.dWih1, p.dWhh1};
    for (int e = tid; e < 12288; e += 256) {
      int k2 = e & 255, r = e >> 8;       // r 0..47
      int g = r & 3, uu = (r >> 2) & 1, m = r >> 3;
      const float *row = mats[m] + (size_t)(g * 512 + blk * 2 + uu) * 512;
      wl1[(m * 512 + k2 * 2 + uu) * 4 + g] = packh(row[2 * k2], row[2 * k2 + 1]);
    }
    for (int e = tid; e < 2048; e += 256) {  // W' = dec_Wih0 @ fcW -> slot 6
      int uu = e >> 10, rem = e & 1023, g = rem & 3, k2 = rem >> 2;
      const float *wr = p.dWih0 + (size_t)(g * 512 + blk * 2 + uu) * 6;
      float v0 = 0.f, v1 = 0.f;
#pragma unroll
      for (int i = 0; i < 6; ++i) {
        v0 = fmaf(wr[i], p.fcW[i * 512 + 2 * k2], v0);
        v1 = fmaf(wr[i], p.fcW[i * 512 + 2 * k2 + 1], v1);
      }
      wl1[(6 * 512 + k2 * 2 + uu) * 4 + g] = packh(v0, v1);
    }
    if (tid < 40) {  // fused biases: be0|be1|bd1|b''|bd0
      int f = tid >> 3, k = tid & 7, uu = k >> 2, g = k & 3;
      int r2 = g * 512 + blk * 2 + uu;
      float v;
      if (f == 0) v = p.ebih0[r2] + p.ebhh0[r2];
      else if (f == 1) v = p.ebih1[r2] + p.ebhh1[r2];
      else if (f == 2) v = p.dbih1[r2] + p.dbhh1[r2];
      else {
        v = p.dbih0[r2] + p.dbhh0[r2];
        if (f == 3)
#pragma unroll
          for (int i = 0; i < 6; ++i) v = fmaf(p.dWih0[(size_t)r2 * 6 + i], p.fcb[i], v);
      }
      bbuf[tid] = v;
    } else if (tid >= 64 && tid < 112) {
      int idx = tid - 64, uu = idx / 24, rem = idx % 24, g = rem / 6, i = rem % 6;
      wxe[idx] = p.eWih0[(size_t)(g * 512 + blk * 2 + uu) * 6 + i];
    } else if (tid >= 128 && tid < 176) {
      int idx = tid - 128, uu = idx / 24, rem = idx % 24, g = rem / 6, i = rem % 6;
      wxd[idx] = p.dWih0[(size_t)(g * 512 + blk * 2 + uu) * 6 + i];
    }
  }
  // ---- init: transpose src -> srcT; seed decoder input ----
  for (int e = blk * 256 + tid; e < 196608; e += 65536) {
    int bb = e & 127, rest = e >> 7, i = rest % 6, t = rest / 6;
    srcT[t * 768 + i * 128 + bb] = p.src[((size_t)bb * 256 + t) * 6 + i];
  }
  {
    int g0 = blk * 256 + tid;
    if (g0 < 768) {
      int bb = g0 & 127, i = g0 >> 7;
      outp[i * 128 + bb] = p.src[((size_t)bb * 256 + 255) * 6 + i];
    }
  }
  float c0[2] = {0.f, 0.f}, c1[2] = {0.f, 0.f};
  unsigned gen = 1;
  arrive(flags, gen, tid, blk);
  waitbar(flags, gen, tid);

#define WQ(m) (wl4 + (m) * 512 + kh * 256)
#define HST(buf) ((const unsigned *)(buf) + kh * 16384 + b)
#define RADD(gb, slot) { float4 v = redux[slot][b]; \
    G[(gb)] += v.x; G[(gb) + 1] += v.y; G[(gb) + 2] += v.z; G[(gb) + 3] += v.w; }

  // ================= encoder: layer0 & layer1 pipelined (lag 1) ============
  for (int t = 0; t <= 256; ++t) {
    float A16[16], A8[8];
#pragma unroll
    for (int i = 0; i < 16; ++i) A16[i] = 0.f;
#pragma unroll
    for (int i = 0; i < 8; ++i) A8[i] = 0.f;
    dotq2(A16, WQ(0), WQ(1), HST(hp0r[t & 1]));   // eWhh0 + eWih1 share h0
    dotq1(A8, WQ(2), HST(hp1r[(t + 1) & 1]));     // eWhh1 @ h1[t-2]
    if (kh) {
      redux[0][b] = make_float4(A16[0], A16[1], A16[2], A16[3]);
      redux[1][b] = make_float4(A16[4], A16[5], A16[6], A16[7]);
      redux[2][b] = make_float4(A16[8], A16[9], A16[10], A16[11]);
      redux[3][b] = make_float4(A16[12], A16[13], A16[14], A16[15]);
      redux[4][b] = make_float4(A8[0], A8[1], A8[2], A8[3]);
      redux[5][b] = make_float4(A8[4], A8[5], A8[6], A8[7]);
    }
    __syncthreads();
    if (kh == 0) {
      float G[24];
#pragma unroll
      for (int i = 0; i < 16; ++i) G[i] = A16[i];
#pragma unroll
      for (int i = 0; i < 8; ++i) G[16 + i] = A8[i];
      { RADD(0, 0) RADD(4, 1) RADD(8, 2) RADD(12, 3) RADD(16, 4) RADD(20, 5) }
      if (t < 256) {  // layer0
        float xv[6], h0v[2];
#pragma unroll
        for (int i = 0; i < 6; ++i) xv[i] = srcT[t * 768 + i * 128 + b];
#pragma unroll
        for (int uu = 0; uu < 2; ++uu) {
          float g4[4];
#pragma unroll
          for (int g = 0; g < 4; ++g) {
            float v = G[uu * 4 + g] + bbuf[uu * 4 + g];
#pragma unroll
            for (int i = 0; i < 6; ++i) v = fmaf(wxe[uu * 24 + g * 6 + i], xv[i], v);
            g4[g] = v;
          }
          float ig = sigf(g4[0]), fg = sigf(g4[1]), gg = tanhf(g4[2]), og = sigf(g4[3]);
          c0[uu] = fg * c0[uu] + ig * gg;
          h0v[uu] = og * tanhf(c0[uu]);
        }
        hp0r[(t + 1) & 1][blk * 128 + b] = packh(h0v[0], h0v[1]);
      }
      if (t >= 1) {  // layer1
        float h1v[2];
#pragma unroll
        for (int uu = 0; uu < 2; ++uu) {
          float g4[4];
#pragma unroll
          for (int g = 0; g < 4; ++g)
            g4[g] = G[8 + uu * 4 + g] + G[16 + uu * 4 + g] + bbuf[8 + uu * 4 + g];
          float ig = sigf(g4[0]), fg = sigf(g4[1]), gg = tanhf(g4[2]), og = sigf(g4[3]);
          c1[uu] = fg * c1[uu] + ig * gg;
          h1v[uu] = og * tanhf(c1[uu]);
        }
        hp1r[t & 1][blk * 128 + b] = packh(h1v[0], h1v[1]);
      }
    }
    arrive(flags, ++gen, tid, blk);
    waitbar(flags, gen, tid);
  }
  // enc final: h0 in hp0r[0], h1 in hp1r[0]; c0,c1 in registers.

  // ========== decoder: 2 rounds/step, pre-dots hide barrier waits ==========
  for (int s = 0; s < 256; ++s) {
    // ---- R_A: dec layer0 (+ W'@h1 fused fc; saves Whh1d partial for R_B) --
    float A3[8];
#pragma unroll
    for (int i = 0; i < 8; ++i) A3[i] = 0.f;
    dotq1(A3, WQ(3), HST(hp0r[s & 1]));  // pre-wait: stream synced last gen
    if (s) waitbar(flags, gen, tid);
    float AA[16];
#pragma unroll
    for (int i = 0; i < 16; ++i) AA[i] = 0.f;
    if (s == 0) {
      dotq1(AA + 8, WQ(5), HST(hp1r[0]));  // Whh1d partial only
    } else {
      dotq2(AA, WQ(6), WQ(5), HST(hp1r[s & 1]));  // W' + Whh1d share h1
      fc_emit(hp1r[s & 1], p.fcW, p.fcb, p.out, s - 1, tid, blk);
    }
    if (kh) {
      redux[0][b] = make_float4(A3[0], A3[1], A3[2], A3[3]);
      redux[1][b] = make_float4(A3[4], A3[5], A3[6], A3[7]);
      redux[2][b] = make_float4(AA[0], AA[1], AA[2], AA[3]);
      redux[3][b] = make_float4(AA[4], AA[5], AA[6], AA[7]);
    }
    __syncthreads();
    if (kh == 0) {
      float G[8];
#pragma unroll
      for (int i = 0; i < 8; ++i) G[i] = A3[i] + AA[i];
      { RADD(0, 0) RADD(4, 1) RADD(0, 2) RADD(4, 3) }
      float bq[8];
      if (s == 0) {
        float xv[6];
#pragma unroll
        for (int i = 0; i < 6; ++i) xv[i] = outp[i * 128 + b];
#pragma unroll
        for (int k = 0; k < 8; ++k) {
          int uu = k >> 2, g = k & 3;
          float v = bbuf[32 + k];
#pragma unroll
          for (int i = 0; i < 6; ++i) v = fmaf(wxd[uu * 24 + g * 6 + i], xv[i], v);
          bq[k] = v;
        }
      } else {
#pragma unroll
        for (int k = 0; k < 8; ++k) bq[k] = bbuf[24 + k];
      }
      float h0v[2];
#pragma unroll
      for (int uu = 0; uu < 2; ++uu) {
        float ig = sigf(G[uu * 4 + 0] + bq[uu * 4 + 0]);
        float fg = sigf(G[uu * 4 + 1] + bq[uu * 4 + 1]);
        float gg = tanhf(G[uu * 4 + 2] + bq[uu * 4 + 2]);
        float og = sigf(G[uu * 4 + 3] + bq[uu * 4 + 3]);
        c0[uu] = fg * c0[uu] + ig * gg;
        h0v[uu] = og * tanhf(c0[uu]);
      }
      hp0r[(s + 1) & 1][blk * 128 + b] = packh(h0v[0], h0v[1]);
    }
    arrive(flags, ++gen, tid, blk);
    // ---- R_B: dec layer1 = Whh1d-partial (saved) + Wih1d @ h0[s] (new) ----
    waitbar(flags, gen, tid);
    float A4[8];
#pragma unroll
    for (int i = 0; i < 8; ++i) A4[i] = AA[8 + i];  // saved partial
    dotq1(A4, WQ(4), HST(hp0r[(s + 1) & 1]));
    if (kh) {
      redux[0][b] = make_float4(A4[0], A4[1], A4[2], A4[3]);
      redux[1][b] = make_float4(A4[4], A4[5], A4[6], A4[7]);
    }
    __syncthreads();
    if (kh == 0) {
      float G[8];
#pragma unroll
      for (int i = 0; i < 8; ++i) G[i] = A4[i];
      { RADD(0, 0) RADD(4, 1) }
      float h1v[2];
#pragma unroll
      for (int uu = 0; uu < 2; ++uu) {
        float ig = sigf(G[uu * 4 + 0] + bbuf[16 + uu * 4 + 0]);
        float fg = sigf(G[uu * 4 + 1] + bbuf[16 + uu * 4 + 1]);
        float gg = tanhf(G[uu * 4 + 2] + bbuf[16 + uu * 4 + 2]);
        float og = sigf(G[uu * 4 + 3] + bbuf[16 + uu * 4 + 3]);
        c1[uu] = fg * c1[uu] + ig * gg;
        h1v[uu] = og * tanhf(c1[uu]);
      }
      hp1r[(s + 1) & 1][blk * 128 + b] = packh(h1v[0], h1v[1]);
    }
    arrive(flags, ++gen, tid, blk);
  }
  waitbar(flags, gen, tid);
  fc_emit(hp1r[0], p.fcW, p.fcb, p.out, 255, tid, blk);  // tail out[255]
}

extern "C" void kernel_launch(void *const *d_in, const int *in_sizes, int n_in,
                              void *d_out, int out_size, void *d_ws, size_t ws_size,
                              hipStream_t stream) {
  (void)in_sizes; (void)n_in; (void)out_size; (void)ws_size;
  P19 p;
  p.src = (const float *)d_in[0];
  p.eWih0 = (const float *)d_in[1];  p.eWhh0 = (const float *)d_in[2];
  p.ebih0 = (const float *)d_in[3];  p.ebhh0 = (const float *)d_in[4];
  p.eWih1 = (const float *)d_in[5];  p.eWhh1 = (const float *)d_in[6];
  p.ebih1 = (const float *)d_in[7];  p.ebhh1 = (const float *)d_in[8];
  p.dWih0 = (const float *)d_in[9];  p.dWhh0 = (const float *)d_in[10];
  p.dbih0 = (const float *)d_in[11]; p.dbhh0 = (const float *)d_in[12];
  p.dWih1 = (const float *)d_in[13]; p.dWhh1 = (const float *)d_in[14];
  p.dbih1 = (const float *)d_in[15]; p.dbhh1 = (const float *)d_in[16];
  p.fcW = (const float *)d_in[17];   p.fcb = (const float *)d_in[18];
  p.out = (float *)d_out;
  p.ws = (float *)d_ws;

  // zero flags + 4 packed-h parity buffers (outp/srcT written by kernel init)
  hipMemsetAsync(d_ws, 0, (size_t)(8256 + 4 * 32768) * sizeof(float), stream);
  seq2seq_kernel<<<dim3(256), dim3(256), 0, stream>>>(p);
}

// Round 10
// 12393.119 us; speedup vs baseline: 9.1470x; 1.8465x over previous
//
#include <hip/hip_runtime.h>
#include <hip/hip_fp16.h>

// ---------------- parameters (all inputs fp32; output fp32) ----------------
struct P19 {
  const float *src;
  const float *eWih0, *eWhh0, *ebih0, *ebhh0;
  const float *eWih1, *eWhh1, *ebih1, *ebhh1;
  const float *dWih0, *dWhh0, *dbih0, *dbhh0;
  const float *dWih1, *dWhh1, *dbih1, *dbhh1;
  const float *fcW, *fcb;
  float *out;
  float *ws;
};

typedef _Float16 h2v __attribute__((ext_vector_type(2)));

__device__ __forceinline__ float sigf(float x) { return 1.f / (1.f + __expf(-x)); }

__device__ __forceinline__ unsigned packh(float a, float b2) {
  __half2 h2 = __floats2half2_rn(a, b2);
  return *(const unsigned *)&h2;
}

// Uncached (L3 coherence-point) accessors. AGENT-scope relaxed atomics emit
// sc0+sc1 loads/stores: bypass L1/L2, no buffer_wbl2 / buffer_inv fences.
// Cross-XCD protocol: syncthreads drains vmcnt(0) per wave (so all h stores
// are L3-visible) BEFORE the flag store; pollers read flags+h straight from
// L3 -> no stale caches, no __threadfence needed anywhere.
__device__ __forceinline__ unsigned ldh(const unsigned *p) {
  return __hip_atomic_load((const unsigned *)p, __ATOMIC_RELAXED, __HIP_MEMORY_SCOPE_AGENT);
}
__device__ __forceinline__ void sth(unsigned *p, unsigned v) {
  __hip_atomic_store(p, v, __ATOMIC_RELAXED, __HIP_MEMORY_SCOPE_AGENT);
}
__device__ __forceinline__ void sthf(float *p, float v) {
  __hip_atomic_store(p, v, __ATOMIC_RELAXED, __HIP_MEMORY_SCOPE_AGENT);
}
__device__ __forceinline__ float ldhf(const float *p) {
  return __hip_atomic_load((const float *)p, __ATOMIC_RELAXED, __HIP_MEMORY_SCOPE_AGENT);
}

__device__ __forceinline__ float dot2(unsigned h, unsigned w, float acc) {
#if __has_builtin(__builtin_amdgcn_fdot2)
  return __builtin_amdgcn_fdot2(*(h2v *)&h, *(h2v *)&w, acc, false);
#else
  float2 hf = __half22float2(*(const __half2 *)&h);
  float2 wf = __half22float2(*(const __half2 *)&w);
  return fmaf(hf.x, wf.x, fmaf(hf.y, wf.y, acc));
#endif
}

// ---- split-phase distributed-flag grid barrier, FENCELESS ----------------
__device__ __forceinline__ void arrive(unsigned *flags, unsigned gen, int tid, int blk) {
  __syncthreads();  // drains vmcnt(0) per wave: all agent-stores are in L3
  if (tid == 0) sth(flags + blk * 32, gen);
}
__device__ __forceinline__ void waitbar(unsigned *flags, unsigned gen, int tid) {
  {
    unsigned *f = flags + tid * 32;
    int g = 0;
    while (ldh(f) < gen) {
      __builtin_amdgcn_s_sleep(8);
      if (++g > (1 << 16)) break;  // safety: never deadlock the bench
    }
  }
  __syncthreads();  // all threads saw their flag; h reads below are uncached
}

// ---- half-dots: thread covers BOTH units (8 gate-rows) over 128 k2 -------
// Double-buffered 32-dword chunks; 256-thr blocks -> full VGPR budget
// (r7/r8 lesson: 512-thr blocks cap at 128 VGPR -> scratch spills).
__device__ __forceinline__ void dotq1(float *A, const uint4 *__restrict__ wq,
                                      const unsigned *__restrict__ hq) {
  unsigned ca[32], cb[32];
#pragma unroll
  for (int c = 0; c < 32; ++c) ca[c] = ldh(hq + c * 128);
  for (int j = 0; j < 4; j += 2) {
#pragma unroll
    for (int c = 0; c < 32; ++c) cb[c] = ldh(hq + ((j + 1) * 32 + c) * 128);
#pragma unroll
    for (int c = 0; c < 32; ++c) {
      int k2 = j * 32 + c;
      uint4 w0 = wq[k2 * 2], w1 = wq[k2 * 2 + 1];
      unsigned h = ca[c];
      A[0] = dot2(h, w0.x, A[0]); A[1] = dot2(h, w0.y, A[1]);
      A[2] = dot2(h, w0.z, A[2]); A[3] = dot2(h, w0.w, A[3]);
      A[4] = dot2(h, w1.x, A[4]); A[5] = dot2(h, w1.y, A[5]);
      A[6] = dot2(h, w1.z, A[6]); A[7] = dot2(h, w1.w, A[7]);
    }
#pragma unroll
    for (int c = 0; c < 32; ++c) ca[c] = ldh(hq + ((((j + 2) & 3)) * 32 + c) * 128);
#pragma unroll
    for (int c = 0; c < 32; ++c) {
      int k2 = (j + 1) * 32 + c;
      uint4 w0 = wq[k2 * 2], w1 = wq[k2 * 2 + 1];
      unsigned h = cb[c];
      A[0] = dot2(h, w0.x, A[0]); A[1] = dot2(h, w0.y, A[1]);
      A[2] = dot2(h, w0.z, A[2]); A[3] = dot2(h, w0.w, A[3]);
      A[4] = dot2(h, w1.x, A[4]); A[5] = dot2(h, w1.y, A[5]);
      A[6] = dot2(h, w1.z, A[6]); A[7] = dot2(h, w1.w, A[7]);
    }
  }
}
__device__ __forceinline__ void dotq2(float *A, const uint4 *__restrict__ w0q,
                                      const uint4 *__restrict__ w1q,
                                      const unsigned *__restrict__ hq) {
  unsigned ca[32], cb[32];
#pragma unroll
  for (int c = 0; c < 32; ++c) ca[c] = ldh(hq + c * 128);
  for (int j = 0; j < 4; j += 2) {
#pragma unroll
    for (int c = 0; c < 32; ++c) cb[c] = ldh(hq + ((j + 1) * 32 + c) * 128);
#pragma unroll
    for (int c = 0; c < 32; ++c) {
      int k2 = j * 32 + c;
      uint4 a0 = w0q[k2 * 2], a1 = w0q[k2 * 2 + 1];
      uint4 b0 = w1q[k2 * 2], b1 = w1q[k2 * 2 + 1];
      unsigned h = ca[c];
      A[0] = dot2(h, a0.x, A[0]);   A[1] = dot2(h, a0.y, A[1]);
      A[2] = dot2(h, a0.z, A[2]);   A[3] = dot2(h, a0.w, A[3]);
      A[4] = dot2(h, a1.x, A[4]);   A[5] = dot2(h, a1.y, A[5]);
      A[6] = dot2(h, a1.z, A[6]);   A[7] = dot2(h, a1.w, A[7]);
      A[8] = dot2(h, b0.x, A[8]);   A[9] = dot2(h, b0.y, A[9]);
      A[10] = dot2(h, b0.z, A[10]); A[11] = dot2(h, b0.w, A[11]);
      A[12] = dot2(h, b1.x, A[12]); A[13] = dot2(h, b1.y, A[13]);
      A[14] = dot2(h, b1.z, A[14]); A[15] = dot2(h, b1.w, A[15]);
    }
#pragma unroll
    for (int c = 0; c < 32; ++c) ca[c] = ldh(hq + ((((j + 2) & 3)) * 32 + c) * 128);
#pragma unroll
    for (int c = 0; c < 32; ++c) {
      int k2 = (j + 1) * 32 + c;
      uint4 a0 = w0q[k2 * 2], a1 = w0q[k2 * 2 + 1];
      uint4 b0 = w1q[k2 * 2], b1 = w1q[k2 * 2 + 1];
      unsigned h = cb[c];
      A[0] = dot2(h, a0.x, A[0]);   A[1] = dot2(h, a0.y, A[1]);
      A[2] = dot2(h, a0.z, A[2]);   A[3] = dot2(h, a0.w, A[3]);
      A[4] = dot2(h, a1.x, A[4]);   A[5] = dot2(h, a1.y, A[5]);
      A[6] = dot2(h, a1.z, A[6]);   A[7] = dot2(h, a1.w, A[7]);
      A[8] = dot2(h, b0.x, A[8]);   A[9] = dot2(h, b0.y, A[9]);
      A[10] = dot2(h, b0.z, A[10]); A[11] = dot2(h, b0.w, A[11]);
      A[12] = dot2(h, b1.x, A[12]); A[13] = dot2(h, b1.y, A[13]);
      A[14] = dot2(h, b1.z, A[14]); A[15] = dot2(h, b1.w, A[15]);
    }
  }
}

__device__ __forceinline__ void fc_emit(const unsigned *__restrict__ h1buf,
                                        const float *__restrict__ fcW,
                                        const float *__restrict__ fcb,
                                        float *__restrict__ out, int sIdx,
                                        int tid, int blk) {
  int q = tid >> 6, l = tid & 63;
  if (q < 3) {
    int o = blk * 3 + q, j = o >> 7, bb = o & 127;
    const unsigned *hc = h1buf + bb;
    const float2 *fw = (const float2 *)(fcW + j * 512);
    float acc = 0.f;
#pragma unroll
    for (int r = 0; r < 4; ++r) {
      int k2 = l + r * 64;
      unsigned d = ldh(hc + k2 * 128);
      float2 hf = __half22float2(*(const __half2 *)&d);
      float2 wv = fw[k2];
      acc = fmaf(wv.x, hf.x, acc);
      acc = fmaf(wv.y, hf.y, acc);
    }
#pragma unroll
    for (int off = 32; off; off >>= 1) acc += __shfl_down(acc, off, 64);
    if (l == 0) out[((size_t)bb * 256 + sIdx) * 6 + j] = acc + fcb[j];
  }
}

__global__ __launch_bounds__(256, 1) void seq2seq_kernel(P19 p) {
  const int tid = threadIdx.x;
  const int blk = blockIdx.x;
  const int b = tid & 127;   // batch lane
  const int kh = tid >> 7;   // k-half 0..1

  float *ws = p.ws;
  unsigned *flags = (unsigned *)ws;  // 256 flags, 128B-spaced
  unsigned *hpB = (unsigned *)(ws + 8256);
  unsigned *hp0r[2] = {hpB, hpB + 32768};           // h0 parity, [k2][b]
  unsigned *hp1r[2] = {hpB + 65536, hpB + 98304};   // h1 parity
  float *outp = ws + 8256 + 131072;                 // dec seed [j][b] 6*128
  float *srcT = outp + 768;                         // [t][i][b] 256*6*128

  // LDS: 7 matrices x 256 k2 x 2 units x (4 gates half2) = 56 KiB
  __shared__ __align__(16) uint4 wl4[3584];
  __shared__ float4 redux[6][128];  // 12 KiB: kh=1 partial-dot exchange
  __shared__ float wxe[48], wxd[48], bbuf[40];
  unsigned *wl1 = (unsigned *)wl4;

  {  // ---- stage weights (fp16 pairs) into LDS, once ----
    const float *mats[6] = {p.eWhh0, p.eWih1, p.eWhh1, p.dWhh0, p.dWih1, p.dWhh1};
    for (int e = tid; e < 12288; e += 256) {
      int k2 = e & 255, r = e >> 8;       // r 0..47
      int g = r & 3, uu = (r >> 2) & 1, m = r >> 3;
      const float *row = mats[m] + (size_t)(g * 512 + blk * 2 + uu) * 512;
      wl1[(m * 512 + k2 * 2 + uu) * 4 + g] = packh(row[2 * k2], row[2 * k2 + 1]);
    }
    for (int e = tid; e < 2048; e += 256) {  // W' = dec_Wih0 @ fcW -> slot 6
      int uu = e >> 10, rem = e & 1023, g = rem & 3, k2 = rem >> 2;
      const float *wr = p.dWih0 + (size_t)(g * 512 + blk * 2 + uu) * 6;
      float v0 = 0.f, v1 = 0.f;
#pragma unroll
      for (int i = 0; i < 6; ++i) {
        v0 = fmaf(wr[i], p.fcW[i * 512 + 2 * k2], v0);
        v1 = fmaf(wr[i], p.fcW[i * 512 + 2 * k2 + 1], v1);
      }
      wl1[(6 * 512 + k2 * 2 + uu) * 4 + g] = packh(v0, v1);
    }
    if (tid < 40) {  // fused biases: be0|be1|bd1|b''|bd0
      int f = tid >> 3, k = tid & 7, uu = k >> 2, g = k & 3;
      int r2 = g * 512 + blk * 2 + uu;
      float v;
      if (f == 0) v = p.ebih0[r2] + p.ebhh0[r2];
      else if (f == 1) v = p.ebih1[r2] + p.ebhh1[r2];
      else if (f == 2) v = p.dbih1[r2] + p.dbhh1[r2];
      else {
        v = p.dbih0[r2] + p.dbhh0[r2];
        if (f == 3)
#pragma unroll
          for (int i = 0; i < 6; ++i) v = fmaf(p.dWih0[(size_t)r2 * 6 + i], p.fcb[i], v);
      }
      bbuf[tid] = v;
    } else if (tid >= 64 && tid < 112) {
      int idx = tid - 64, uu = idx / 24, rem = idx % 24, g = rem / 6, i = rem % 6;
      wxe[idx] = p.eWih0[(size_t)(g * 512 + blk * 2 + uu) * 6 + i];
    } else if (tid >= 128 && tid < 176) {
      int idx = tid - 128, uu = idx / 24, rem = idx % 24, g = rem / 6, i = rem % 6;
      wxd[idx] = p.dWih0[(size_t)(g * 512 + blk * 2 + uu) * 6 + i];
    }
  }
  // ---- init: transpose src -> srcT; seed decoder input (agent stores: ----
  // ---- cross-block reads later must see them at the coherence point)  ----
  for (int e = blk * 256 + tid; e < 196608; e += 65536) {
    int bb = e & 127, rest = e >> 7, i = rest % 6, t = rest / 6;
    sthf(&srcT[t * 768 + i * 128 + bb], p.src[((size_t)bb * 256 + t) * 6 + i]);
  }
  {
    int g0 = blk * 256 + tid;
    if (g0 < 768) {
      int bb = g0 & 127, i = g0 >> 7;
      sthf(&outp[i * 128 + bb], p.src[((size_t)bb * 256 + 255) * 6 + i]);
    }
  }
  float c0[2] = {0.f, 0.f}, c1[2] = {0.f, 0.f};
  unsigned gen = 1;
  arrive(flags, gen, tid, blk);
  waitbar(flags, gen, tid);

#define WQ(m) (wl4 + (m) * 512 + kh * 256)
#define HST(buf) ((const unsigned *)(buf) + kh * 16384 + b)
#define RADD(gb, slot) { float4 v = redux[slot][b]; \
    G[(gb)] += v.x; G[(gb) + 1] += v.y; G[(gb) + 2] += v.z; G[(gb) + 3] += v.w; }

  // ================= encoder: layer0 & layer1 pipelined (lag 1) ============
  for (int t = 0; t <= 256; ++t) {
    float A16[16], A8[8];
#pragma unroll
    for (int i = 0; i < 16; ++i) A16[i] = 0.f;
#pragma unroll
    for (int i = 0; i < 8; ++i) A8[i] = 0.f;
    dotq2(A16, WQ(0), WQ(1), HST(hp0r[t & 1]));   // eWhh0 + eWih1 share h0
    dotq1(A8, WQ(2), HST(hp1r[(t + 1) & 1]));     // eWhh1 @ h1[t-2]
    if (kh) {
      redux[0][b] = make_float4(A16[0], A16[1], A16[2], A16[3]);
      redux[1][b] = make_float4(A16[4], A16[5], A16[6], A16[7]);
      redux[2][b] = make_float4(A16[8], A16[9], A16[10], A16[11]);
      redux[3][b] = make_float4(A16[12], A16[13], A16[14], A16[15]);
      redux[4][b] = make_float4(A8[0], A8[1], A8[2], A8[3]);
      redux[5][b] = make_float4(A8[4], A8[5], A8[6], A8[7]);
    }
    __syncthreads();
    if (kh == 0) {
      float G[24];
#pragma unroll
      for (int i = 0; i < 16; ++i) G[i] = A16[i];
#pragma unroll
      for (int i = 0; i < 8; ++i) G[16 + i] = A8[i];
      { RADD(0, 0) RADD(4, 1) RADD(8, 2) RADD(12, 3) RADD(16, 4) RADD(20, 5) }
      if (t < 256) {  // layer0
        float xv[6], h0v[2];
#pragma unroll
        for (int i = 0; i < 6; ++i) xv[i] = srcT[t * 768 + i * 128 + b];
#pragma unroll
        for (int uu = 0; uu < 2; ++uu) {
          float g4[4];
#pragma unroll
          for (int g = 0; g < 4; ++g) {
            float v = G[uu * 4 + g] + bbuf[uu * 4 + g];
#pragma unroll
            for (int i = 0; i < 6; ++i) v = fmaf(wxe[uu * 24 + g * 6 + i], xv[i], v);
            g4[g] = v;
          }
          float ig = sigf(g4[0]), fg = sigf(g4[1]), gg = tanhf(g4[2]), og = sigf(g4[3]);
          c0[uu] = fg * c0[uu] + ig * gg;
          h0v[uu] = og * tanhf(c0[uu]);
        }
        sth(&hp0r[(t + 1) & 1][blk * 128 + b], packh(h0v[0], h0v[1]));
      }
      if (t >= 1) {  // layer1
        float h1v[2];
#pragma unroll
        for (int uu = 0; uu < 2; ++uu) {
          float g4[4];
#pragma unroll
          for (int g = 0; g < 4; ++g)
            g4[g] = G[8 + uu * 4 + g] + G[16 + uu * 4 + g] + bbuf[8 + uu * 4 + g];
          float ig = sigf(g4[0]), fg = sigf(g4[1]), gg = tanhf(g4[2]), og = sigf(g4[3]);
          c1[uu] = fg * c1[uu] + ig * gg;
          h1v[uu] = og * tanhf(c1[uu]);
        }
        sth(&hp1r[t & 1][blk * 128 + b], packh(h1v[0], h1v[1]));
      }
    }
    arrive(flags, ++gen, tid, blk);
    waitbar(flags, gen, tid);
  }
  // enc final: h0 in hp0r[0], h1 in hp1r[0]; c0,c1 in registers.

  // ========== decoder: 2 rounds/step, pre-dots hide barrier waits ==========
  for (int s = 0; s < 256; ++s) {
    // ---- R_A: dec layer0 (+ W'@h1 fused fc; saves Whh1d partial for R_B) --
    float A3[8];
#pragma unroll
    for (int i = 0; i < 8; ++i) A3[i] = 0.f;
    dotq1(A3, WQ(3), HST(hp0r[s & 1]));  // pre-wait: stream synced last gen
    if (s) waitbar(flags, gen, tid);
    float AA[16];
#pragma unroll
    for (int i = 0; i < 16; ++i) AA[i] = 0.f;
    if (s == 0) {
      dotq1(AA + 8, WQ(5), HST(hp1r[0]));  // Whh1d partial only
    } else {
      dotq2(AA, WQ(6), WQ(5), HST(hp1r[s & 1]));  // W' + Whh1d share h1
      fc_emit(hp1r[s & 1], p.fcW, p.fcb, p.out, s - 1, tid, blk);
    }
    if (kh) {
      redux[0][b] = make_float4(A3[0], A3[1], A3[2], A3[3]);
      redux[1][b] = make_float4(A3[4], A3[5], A3[6], A3[7]);
      redux[2][b] = make_float4(AA[0], AA[1], AA[2], AA[3]);
      redux[3][b] = make_float4(AA[4], AA[5], AA[6], AA[7]);
    }
    __syncthreads();
    if (kh == 0) {
      float G[8];
#pragma unroll
      for (int i = 0; i < 8; ++i) G[i] = A3[i] + AA[i];
      { RADD(0, 0) RADD(4, 1) RADD(0, 2) RADD(4, 3) }
      float bq[8];
      if (s == 0) {
        float xv[6];
#pragma unroll
        for (int i = 0; i < 6; ++i) xv[i] = ldhf(&outp[i * 128 + b]);
#pragma unroll
        for (int k = 0; k < 8; ++k) {
          int uu = k >> 2, g = k & 3;
          float v = bbuf[32 + k];
#pragma unroll
          for (int i = 0; i < 6; ++i) v = fmaf(wxd[uu * 24 + g * 6 + i], xv[i], v);
          bq[k] = v;
        }
      } else {
#pragma unroll
        for (int k = 0; k < 8; ++k) bq[k] = bbuf[24 + k];
      }
      float h0v[2];
#pragma unroll
      for (int uu = 0; uu < 2; ++uu) {
        float ig = sigf(G[uu * 4 + 0] + bq[uu * 4 + 0]);
        float fg = sigf(G[uu * 4 + 1] + bq[uu * 4 + 1]);
        float gg = tanhf(G[uu * 4 + 2] + bq[uu * 4 + 2]);
        float og = sigf(G[uu * 4 + 3] + bq[uu * 4 + 3]);
        c0[uu] = fg * c0[uu] + ig * gg;
        h0v[uu] = og * tanhf(c0[uu]);
      }
      sth(&hp0r[(s + 1) & 1][blk * 128 + b], packh(h0v[0], h0v[1]));
    }
    arrive(flags, ++gen, tid, blk);
    // ---- R_B: dec layer1 = Whh1d-partial (saved) + Wih1d @ h0[s] (new) ----
    waitbar(flags, gen, tid);
    float A4[8];
#pragma unroll
    for (int i = 0; i < 8; ++i) A4[i] = AA[8 + i];  // saved partial
    dotq1(A4, WQ(4), HST(hp0r[(s + 1) & 1]));
    if (kh) {
      redux[0][b] = make_float4(A4[0], A4[1], A4[2], A4[3]);
      redux[1][b] = make_float4(A4[4], A4[5], A4[6], A4[7]);
    }
    __syncthreads();
    if (kh == 0) {
      float G[8];
#pragma unroll
      for (int i = 0; i < 8; ++i) G[i] = A4[i];
      { RADD(0, 0) RADD(4, 1) }
      float h1v[2];
#pragma unroll
      for (int uu = 0; uu < 2; ++uu) {
        float ig = sigf(G[uu * 4 + 0] + bbuf[16 + uu * 4 + 0]);
        float fg = sigf(G[uu * 4 + 1] + bbuf[16 + uu * 4 + 1]);
        float gg = tanhf(G[uu * 4 + 2] + bbuf[16 + uu * 4 + 2]);
        float og = sigf(G[uu * 4 + 3] + bbuf[16 + uu * 4 + 3]);
        c1[uu] = fg * c1[uu] + ig * gg;
        h1v[uu] = og * tanhf(c1[uu]);
      }
      sth(&hp1r[(s + 1) & 1][blk * 128 + b], packh(h1v[0], h1v[1]));
    }
    arrive(flags, ++gen, tid, blk);
  }
  waitbar(flags, gen, tid);
  fc_emit(hp1r[0], p.fcW, p.fcb, p.out, 255, tid, blk);  // tail out[255]
}

extern "C" void kernel_launch(void *const *d_in, const int *in_sizes, int n_in,
                              void *d_out, int out_size, void *d_ws, size_t ws_size,
                              hipStream_t stream) {
  (void)in_sizes; (void)n_in; (void)out_size; (void)ws_size;
  P19 p;
  p.src = (const float *)d_in[0];
  p.eWih0 = (const float *)d_in[1];  p.eWhh0 = (const float *)d_in[2];
  p.ebih0 = (const float *)d_in[3];  p.ebhh0 = (const float *)d_in[4];
  p.eWih1 = (const float *)d_in[5];  p.eWhh1 = (const float *)d_in[6];
  p.ebih1 = (const float *)d_in[7];  p.ebhh1 = (const float *)d_in[8];
  p.dWih0 = (const float *)d_in[9];  p.dWhh0 = (const float *)d_in[10];
  p.dbih0 = (const float *)d_in[11]; p.dbhh0 = (const float *)d_in[12];
  p.dWih1 = (const float *)d_in[13]; p.dWhh1 = (const float *)d_in[14];
  p.dbih1 = (const float *)d_in[15]; p.dbhh1 = (const float *)d_in[16];
  p.fcW = (const float *)d_in[17];   p.fcb = (const float *)d_in[18];
  p.out = (float *)d_out;
  p.ws = (float *)d_ws;

  // zero flags + 4 packed-h parity buffers (outp/srcT written by kernel init)
  hipMemsetAsync(d_ws, 0, (size_t)(8256 + 4 * 32768) * sizeof(float), stream);
  seq2seq_kernel<<<dim3(256), dim3(256), 0, stream>>>(p);
}